// Round 1
// baseline (112.974 us; speedup 1.0000x reference)
//
#include <hip/hip_runtime.h>
#include <math.h>

// RansacRouting: B=32, I=1152, O=10, D=16, H=10, S=922
// v[b,o,:] == Mu[b,o,:,h*] where h* = argmin_h losses[b,o,h]  (since r is 0/1
// and final weighted average over chosen subset == the subset weighted mean).

#define B_    32
#define I_    1152
#define O_    10
#define D_    16
#define H_    10
#define S_    922
#define MASKW 36      // 1152/32 bitmask words
#define NT    640     // 10 waves: wave w owns hypothesis h=w

__global__ __launch_bounds__(NT, 1) void ransac_kernel(
    const float* __restrict__ up,      // [B,I,O,D]
    const int*   __restrict__ sidx,    // [B,S,O,H] (int32)
    float*       __restrict__ out)     // [B,O,D]
{
    __shared__ float    u_t[D_][I_];       // 73728 B, transposed: conflict-free lane-i reads
    __shared__ float    vn[I_];            // 4608 B
    __shared__ unsigned mask[H_][MASKW];   // 1440 B
    __shared__ float    Mu[D_][H_];        // 640 B
    __shared__ double   losses[H_];        // 80 B
    __shared__ int      hstar;

    const int bo   = blockIdx.x;
    const int b    = bo / O_;
    const int o    = bo - b * O_;
    const int tid  = threadIdx.x;
    const int lane = tid & 63;
    const int wv   = tid >> 6;

    // --- zero hypothesis masks ---
    for (int j = tid; j < H_ * MASKW; j += NT)
        ((unsigned*)mask)[j] = 0u;
    __syncthreads();

    // --- scatter sample indices into bitmasks ---
    const int* sb = sidx + (size_t)b * (S_ * O_ * H_) + o * H_;
    for (int j = tid; j < S_ * H_; j += NT) {
        int s = j / H_;
        int h = j - s * H_;
        int idx = sb[s * (O_ * H_) + h];
        atomicOr(&mask[h][idx >> 5], 1u << (idx & 31));
    }

    // --- stage u rows (16 contiguous floats each) into LDS transposed; norms ---
    const float* ub = up + (size_t)b * (I_ * O_ * D_) + o * D_;
    for (int i = tid; i < I_; i += NT) {
        const float4* p = (const float4*)(ub + (size_t)i * (O_ * D_));
        float4 q0 = p[0], q1 = p[1], q2 = p[2], q3 = p[3];
        float s = q0.x*q0.x + q0.y*q0.y + q0.z*q0.z + q0.w*q0.w
                + q1.x*q1.x + q1.y*q1.y + q1.z*q1.z + q1.w*q1.w
                + q2.x*q2.x + q2.y*q2.y + q2.z*q2.z + q2.w*q2.w
                + q3.x*q3.x + q3.y*q3.y + q3.z*q3.z + q3.w*q3.w;
        vn[i] = sqrtf(s);   // safe_l2norm: sqrt(0)==0 anyway
        u_t[ 0][i]=q0.x; u_t[ 1][i]=q0.y; u_t[ 2][i]=q0.z; u_t[ 3][i]=q0.w;
        u_t[ 4][i]=q1.x; u_t[ 5][i]=q1.y; u_t[ 6][i]=q1.z; u_t[ 7][i]=q1.w;
        u_t[ 8][i]=q2.x; u_t[ 9][i]=q2.y; u_t[10][i]=q2.z; u_t[11][i]=q2.w;
        u_t[12][i]=q3.x; u_t[13][i]=q3.y; u_t[14][i]=q3.z; u_t[15][i]=q3.w;
    }
    __syncthreads();

    // --- per-hypothesis weighted mean Mu[:,h] (wave wv == hypothesis h) ---
    const int h = wv;
    float num[D_];
    #pragma unroll
    for (int d = 0; d < D_; ++d) num[d] = 0.f;
    float den = 0.f;
    for (int i = lane; i < I_; i += 64) {
        unsigned bit = (mask[h][i >> 5] >> (i & 31)) & 1u;
        float w = bit ? vn[i] : 0.f;     // predicated, no divergence
        den += w;
        #pragma unroll
        for (int d = 0; d < D_; ++d) num[d] = fmaf(w, u_t[d][i], num[d]);
    }
    #pragma unroll
    for (int off = 32; off; off >>= 1) {
        den += __shfl_xor(den, off, 64);
        #pragma unroll
        for (int d = 0; d < D_; ++d) num[d] += __shfl_xor(num[d], off, 64);
    }
    if (lane == 0) {
        float rd = 1.f / den;
        #pragma unroll
        for (int d = 0; d < D_; ++d) Mu[d][h] = num[d] * rd;
    }
    __syncthreads();

    // --- losses[h] = sum_i ||u_i - Mu_h||  (all 1152 i, fp64 accumulation) ---
    float muh[D_];
    #pragma unroll
    for (int d = 0; d < D_; ++d) muh[d] = Mu[d][h];
    double loss = 0.0;
    for (int i = lane; i < I_; i += 64) {
        float ss = 0.f;
        #pragma unroll
        for (int d = 0; d < D_; ++d) {
            float df = u_t[d][i] - muh[d];
            ss = fmaf(df, df, ss);
        }
        loss += sqrt((double)ss);
    }
    #pragma unroll
    for (int off = 32; off; off >>= 1)
        loss += __shfl_xor(loss, off, 64);
    if (lane == 0) losses[h] = loss;
    __syncthreads();

    // --- argmin over 10 hypotheses (first-min tie-break like np.argmin) ---
    if (tid == 0) {
        int best = 0; double bl = losses[0];
        #pragma unroll
        for (int hh = 1; hh < H_; ++hh)
            if (losses[hh] < bl) { bl = losses[hh]; best = hh; }
        hstar = best;
    }
    __syncthreads();

    if (tid < D_)
        out[(size_t)bo * D_ + tid] = Mu[tid][hstar];
}

extern "C" void kernel_launch(void* const* d_in, const int* in_sizes, int n_in,
                              void* d_out, int out_size, void* d_ws, size_t ws_size,
                              hipStream_t stream) {
    const float* up   = (const float*)d_in[0];
    const int*   sidx = (const int*)d_in[1];
    float*       out  = (float*)d_out;
    ransac_kernel<<<B_ * O_, NT, 0, stream>>>(up, sidx, out);
}

// Round 2
// 106.958 us; speedup vs baseline: 1.0563x; 1.0563x over previous
//
#include <hip/hip_runtime.h>
#include <math.h>

// RansacRouting: B=32, I=1152, O=10, D=16, H=10, S=922
// v[b,o,:] == Mu[b,o,:,h*], h* = argmin_h loss.  Mu over subset computed via
// complement (230 elems): num_h = tot - sum_{i in complement_h} vn_i * u_i.

#define B_    32
#define I_    1152
#define O_    10
#define D_    16
#define H_    10
#define S_    922
#define COMP  230     // I_ - S_
#define MASKW 36      // 1152/32
#define NT    512
#define NW    8

// XOR-swizzled u layout: logical float4 chunk c of row i lives at word
// i*16 + ((c ^ ((i>>1)&3))<<2).  Consecutive-i b128 access covers all 8
// bank-quads per 8 lanes -> conflict-free.
__device__ __forceinline__ int uoff(int i, int c) {
    return i * 16 + (((c ^ ((i >> 1) & 3)) & 3) << 2);
}

// ---- wave64 sum via DPP (VALU pipe, no LDS) -- result valid in lane 63 ----
template <int CTRL, int ROWM>
static __device__ __forceinline__ float dpp_f(float v) {
    return __int_as_float(__builtin_amdgcn_update_dpp(
        0, __float_as_int(v), CTRL, ROWM, 0xf, true));
}
static __device__ __forceinline__ float wave_sum_f32(float v) {
    v += dpp_f<0x111, 0xf>(v);   // row_shr:1
    v += dpp_f<0x112, 0xf>(v);   // row_shr:2
    v += dpp_f<0x114, 0xf>(v);   // row_shr:4
    v += dpp_f<0x118, 0xf>(v);   // row_shr:8
    v += dpp_f<0x142, 0xa>(v);   // row_bcast15 -> rows 1,3
    v += dpp_f<0x143, 0xc>(v);   // row_bcast31 -> rows 2,3
    return v;                    // lane 63 holds the total
}
template <int CTRL, int ROWM>
static __device__ __forceinline__ double dpp_d(double v) {
    long long x = __double_as_longlong(v);
    int lo = (int)(unsigned)(x & 0xffffffffLL);
    int hi = (int)(x >> 32);
    lo = __builtin_amdgcn_update_dpp(0, lo, CTRL, ROWM, 0xf, true);
    hi = __builtin_amdgcn_update_dpp(0, hi, CTRL, ROWM, 0xf, true);
    return __longlong_as_double((long long)(unsigned)lo | ((long long)hi << 32));
}
static __device__ __forceinline__ double wave_sum_f64(double v) {
    v += dpp_d<0x111, 0xf>(v);
    v += dpp_d<0x112, 0xf>(v);
    v += dpp_d<0x114, 0xf>(v);
    v += dpp_d<0x118, 0xf>(v);
    v += dpp_d<0x142, 0xa>(v);
    v += dpp_d<0x143, 0xc>(v);
    return v;
}

__global__ __launch_bounds__(NT, 2) void ransac_kernel(
    const float* __restrict__ up,      // [B,I,O,D]
    const int*   __restrict__ sidx,    // [B,S,O,H]
    float*       __restrict__ out)     // [B,O,D]
{
    __shared__ float          u_s[I_ * 16];        // 73728 B, swizzled chunks
    __shared__ unsigned       mask[H_][MASKW];     // 1440
    __shared__ unsigned short clist[H_][COMP];     // 4600
    __shared__ int            ccount[H_];          // 40
    __shared__ float          Mu_s[H_][D_];        // 640
    __shared__ float          totred[NW][17];      // 544
    __shared__ float          tot[17];             // [0..15]=sum vn*u_d, [16]=sum vn
    __shared__ double         lpart[H_][NW];       // 640
    __shared__ double         losses[H_];          // 80
    __shared__ int            hstar;

    // XCD-aware mapping: the 10 o-blocks of one b share an XCD (L2 reuse of sidx)
    const int blk = blockIdx.x;
    const int xcd = blk & 7, g = blk >> 3;       // g in [0,40)
    const int b   = xcd + 8 * (g / O_);
    const int o   = g - O_ * (g / O_);
    const int bo  = b * O_ + o;

    const int tid  = threadIdx.x;
    const int lane = tid & 63;
    const int wv   = tid >> 6;

    // --- zero masks / counters ---
    for (int j = tid; j < H_ * MASKW; j += NT) ((unsigned*)mask)[j] = 0u;
    if (tid < H_) ccount[tid] = 0;
    __syncthreads();

    // --- stage u rows into LDS (swizzled b128) + accumulate tot = sum vn*u ---
    const float* ub = up + ((size_t)b * I_ * O_ + o) * D_;
    float acc[D_]; float accd = 0.f;
    #pragma unroll
    for (int d = 0; d < D_; ++d) acc[d] = 0.f;
    for (int i = tid; i < I_; i += NT) {
        const float4* p = (const float4*)(ub + (size_t)i * (O_ * D_));
        float4 q0 = p[0], q1 = p[1], q2 = p[2], q3 = p[3];
        float s = q0.x*q0.x + q0.y*q0.y + q0.z*q0.z + q0.w*q0.w
                + q1.x*q1.x + q1.y*q1.y + q1.z*q1.z + q1.w*q1.w
                + q2.x*q2.x + q2.y*q2.y + q2.z*q2.z + q2.w*q2.w
                + q3.x*q3.x + q3.y*q3.y + q3.z*q3.z + q3.w*q3.w;
        float vn = sqrtf(s);
        *(float4*)&u_s[uoff(i,0)] = q0;
        *(float4*)&u_s[uoff(i,1)] = q1;
        *(float4*)&u_s[uoff(i,2)] = q2;
        *(float4*)&u_s[uoff(i,3)] = q3;
        acc[ 0] = fmaf(vn, q0.x, acc[ 0]); acc[ 1] = fmaf(vn, q0.y, acc[ 1]);
        acc[ 2] = fmaf(vn, q0.z, acc[ 2]); acc[ 3] = fmaf(vn, q0.w, acc[ 3]);
        acc[ 4] = fmaf(vn, q1.x, acc[ 4]); acc[ 5] = fmaf(vn, q1.y, acc[ 5]);
        acc[ 6] = fmaf(vn, q1.z, acc[ 6]); acc[ 7] = fmaf(vn, q1.w, acc[ 7]);
        acc[ 8] = fmaf(vn, q2.x, acc[ 8]); acc[ 9] = fmaf(vn, q2.y, acc[ 9]);
        acc[10] = fmaf(vn, q2.z, acc[10]); acc[11] = fmaf(vn, q2.w, acc[11]);
        acc[12] = fmaf(vn, q3.x, acc[12]); acc[13] = fmaf(vn, q3.y, acc[13]);
        acc[14] = fmaf(vn, q3.z, acc[14]); acc[15] = fmaf(vn, q3.w, acc[15]);
        accd += vn;
    }

    // --- scatter hypothesis membership bits ---
    const int* sb = sidx + (size_t)b * (S_ * O_ * H_) + o * H_;
    for (int j = tid; j < S_ * H_; j += NT) {
        int s = j / H_;
        int h = j - s * H_;
        int idx = sb[s * (O_ * H_) + h];
        atomicOr(&mask[h][idx >> 5], 1u << (idx & 31));
    }

    // --- reduce tot partials (DPP, VALU pipe) ---
    #pragma unroll
    for (int d = 0; d < D_; ++d) acc[d] = wave_sum_f32(acc[d]);
    accd = wave_sum_f32(accd);
    if (lane == 63) {
        #pragma unroll
        for (int d = 0; d < D_; ++d) totred[wv][d] = acc[d];
        totred[wv][16] = accd;
    }
    __syncthreads();   // masks complete, totred complete, u_s complete

    if (tid < 17) {
        float t = 0.f;
        #pragma unroll
        for (int w = 0; w < NW; ++w) t += totred[w][tid];
        tot[tid] = t;
    }

    // --- extract complement index lists (230 per h) ---
    for (int h = wv; h < H_; h += NW) {
        if (lane < MASKW) {
            unsigned m = ~mask[h][lane];
            int cnt = __popc(m);
            int base = atomicAdd(&ccount[h], cnt);
            while (m) {
                int bit = __ffs(m) - 1;
                m &= m - 1u;
                clist[h][base++] = (unsigned short)((lane << 5) + bit);
            }
        }
    }
    __syncthreads();   // clist + tot ready

    // --- Mu per hypothesis via complement gather (wave-owns-h) ---
    for (int h = wv; h < H_; h += NW) {
        float na[D_]; float nd = 0.f;
        #pragma unroll
        for (int d = 0; d < D_; ++d) na[d] = 0.f;
        for (int k = lane; k < COMP; k += 64) {
            int i = clist[h][k];
            float4 q0 = *(const float4*)&u_s[uoff(i,0)];
            float4 q1 = *(const float4*)&u_s[uoff(i,1)];
            float4 q2 = *(const float4*)&u_s[uoff(i,2)];
            float4 q3 = *(const float4*)&u_s[uoff(i,3)];
            float s = q0.x*q0.x + q0.y*q0.y + q0.z*q0.z + q0.w*q0.w
                    + q1.x*q1.x + q1.y*q1.y + q1.z*q1.z + q1.w*q1.w
                    + q2.x*q2.x + q2.y*q2.y + q2.z*q2.z + q2.w*q2.w
                    + q3.x*q3.x + q3.y*q3.y + q3.z*q3.z + q3.w*q3.w;
            float vn = sqrtf(s);
            na[ 0] = fmaf(vn, q0.x, na[ 0]); na[ 1] = fmaf(vn, q0.y, na[ 1]);
            na[ 2] = fmaf(vn, q0.z, na[ 2]); na[ 3] = fmaf(vn, q0.w, na[ 3]);
            na[ 4] = fmaf(vn, q1.x, na[ 4]); na[ 5] = fmaf(vn, q1.y, na[ 5]);
            na[ 6] = fmaf(vn, q1.z, na[ 6]); na[ 7] = fmaf(vn, q1.w, na[ 7]);
            na[ 8] = fmaf(vn, q2.x, na[ 8]); na[ 9] = fmaf(vn, q2.y, na[ 9]);
            na[10] = fmaf(vn, q2.z, na[10]); na[11] = fmaf(vn, q2.w, na[11]);
            na[12] = fmaf(vn, q3.x, na[12]); na[13] = fmaf(vn, q3.y, na[13]);
            na[14] = fmaf(vn, q3.z, na[14]); na[15] = fmaf(vn, q3.w, na[15]);
            nd += vn;
        }
        #pragma unroll
        for (int d = 0; d < D_; ++d) na[d] = wave_sum_f32(na[d]);
        nd = wave_sum_f32(nd);
        if (lane == 63) {
            float rd = 1.f / (tot[16] - nd);
            #pragma unroll
            for (int d = 0; d < D_; ++d)
                Mu_s[h][d] = (tot[d] - na[d]) * rd;
        }
    }
    __syncthreads();   // Mu ready

    // --- loss: every wave scans its i-slice against ALL 10 Mu (in registers) ---
    float mu[H_][D_];
    #pragma unroll
    for (int h = 0; h < H_; ++h) {
        float4 m0 = *(const float4*)&Mu_s[h][0];
        float4 m1 = *(const float4*)&Mu_s[h][4];
        float4 m2 = *(const float4*)&Mu_s[h][8];
        float4 m3 = *(const float4*)&Mu_s[h][12];
        mu[h][ 0]=m0.x; mu[h][ 1]=m0.y; mu[h][ 2]=m0.z; mu[h][ 3]=m0.w;
        mu[h][ 4]=m1.x; mu[h][ 5]=m1.y; mu[h][ 6]=m1.z; mu[h][ 7]=m1.w;
        mu[h][ 8]=m2.x; mu[h][ 9]=m2.y; mu[h][10]=m2.z; mu[h][11]=m2.w;
        mu[h][12]=m3.x; mu[h][13]=m3.y; mu[h][14]=m3.z; mu[h][15]=m3.w;
    }
    float musq[H_];
    #pragma unroll
    for (int h = 0; h < H_; ++h) {
        float s = 0.f;
        #pragma unroll
        for (int d = 0; d < D_; ++d) s = fmaf(mu[h][d], mu[h][d], s);
        musq[h] = s;
    }
    double lacc[H_];
    #pragma unroll
    for (int h = 0; h < H_; ++h) lacc[h] = 0.0;

    auto lossStep = [&](int i) {
        float4 q0 = *(const float4*)&u_s[uoff(i,0)];
        float4 q1 = *(const float4*)&u_s[uoff(i,1)];
        float4 q2 = *(const float4*)&u_s[uoff(i,2)];
        float4 q3 = *(const float4*)&u_s[uoff(i,3)];
        float uq[D_] = {q0.x,q0.y,q0.z,q0.w, q1.x,q1.y,q1.z,q1.w,
                        q2.x,q2.y,q2.z,q2.w, q3.x,q3.y,q3.z,q3.w};
        float usq = 0.f;
        #pragma unroll
        for (int d = 0; d < D_; ++d) usq = fmaf(uq[d], uq[d], usq);
        #pragma unroll
        for (int h = 0; h < H_; ++h) {
            float dot = 0.f;
            #pragma unroll
            for (int d = 0; d < D_; ++d) dot = fmaf(uq[d], mu[h][d], dot);
            float d2 = fmaf(-2.f, dot, usq + musq[h]);
            lacc[h] += (double)sqrtf(fmaxf(d2, 0.f));
        }
    };
    lossStep(tid);
    lossStep(tid + NT);
    if (tid >= 384) lossStep(tid + 640);   // waves 6,7 cover [1024,1152)

    #pragma unroll
    for (int h = 0; h < H_; ++h) lacc[h] = wave_sum_f64(lacc[h]);
    if (lane == 63) {
        #pragma unroll
        for (int h = 0; h < H_; ++h) lpart[h][wv] = lacc[h];
    }
    __syncthreads();

    if (tid < H_) {
        double t = 0.0;
        #pragma unroll
        for (int w = 0; w < NW; ++w) t += lpart[tid][w];
        losses[tid] = t;
    }
    __syncthreads();
    if (tid == 0) {
        int best = 0; double bl = losses[0];
        #pragma unroll
        for (int h = 1; h < H_; ++h)
            if (losses[h] < bl) { bl = losses[h]; best = h; }
        hstar = best;
    }
    __syncthreads();
    if (tid < D_)
        out[(size_t)bo * D_ + tid] = Mu_s[hstar][tid];
}

extern "C" void kernel_launch(void* const* d_in, const int* in_sizes, int n_in,
                              void* d_out, int out_size, void* d_ws, size_t ws_size,
                              hipStream_t stream) {
    const float* up   = (const float*)d_in[0];
    const int*   sidx = (const int*)d_in[1];
    float*       out  = (float*)d_out;
    ransac_kernel<<<B_ * O_, NT, 0, stream>>>(up, sidx, out);
}